// Round 2
// baseline (151.126 us; speedup 1.0000x reference)
//
#include <hip/hip_runtime.h>

#define OUTS 14
#define GRIDG 28   // OUTS * sampling_ratio(2)
#define NLEV 4
#define NPIX (OUTS*OUTS)   // 196
#define CG   32            // channels per block
#define NCG  8             // 256 / CG

// v3: single kernel, each output byte written EXACTLY once (no memset node,
// no RMW). Every block streams a float4 zero-fill of its 32ch x 196px slab
// (25 KB) first — stores have no dependencies, so they issue before/under the
// coord-prep phase. Inactive blocks (~95%) then exit. Active blocks compute
// max-across-levels in registers and overwrite their active pixels; the
// __syncthreads between fill and sweep emits s_waitcnt vmcnt(0) before
// s_barrier (hipcc always drains before barriers), so the zero stores are
// globally ordered before the value stores — no race.
//
// The 25 KB per-pixel (idx,weight) LDS table from v2 is dropped (weights
// recomputed per channel-thread from the 3.5 KB per-axis coord arrays: ~25
// VALU per pixel, trivial vs L2-resident gather latency). LDS 29.7 KB -> 4.4
// KB lifts occupancy 5 -> 8 blocks/CU so the fill path matches rocclr-fill
// occupancy (measured 6.7 TB/s on this chip).
//
// Phase 1 keeps the exact torchvision bilinear arithmetic: cumulative roi
// scaling with __f*_rn (no FMA contraction) to match reference
// validity-boundary comparisons bit-for-bit.
__global__ __launch_bounds__(256) void afp_kernel(
    const float* __restrict__ f0, const float* __restrict__ f1,
    const float* __restrict__ f2, const float* __restrict__ f3,
    const float* __restrict__ rois, float* __restrict__ out,
    int R, int C)
{
    __shared__ int   s_lo[2][NLEV][GRIDG];
    __shared__ int   s_hi[2][NLEV][GRIDG];
    __shared__ float s_fr[2][NLEV][GRIDG];
    __shared__ int   s_va[2][NLEV][GRIDG];
    __shared__ int   s_axany[2][NLEV];
    __shared__ int   s_plist[NPIX];
    __shared__ int   s_nact;

    const int bx  = blockIdx.x;
    const int r   = bx >> 3;
    const int cg  = bx & 7;
    const int tid = threadIdx.x;
    const int HS[NLEV] = {224, 112, 56, 28};
    const float* const fp[NLEV] = {f0, f1, f2, f3};
    const int cbase = cg * CG;

    // ---- phase 0: streaming zero-fill of this block's slab (issued first,
    //      no dependencies; completes under phases 1-2) ----
    {
        float4 z = make_float4(0.0f, 0.0f, 0.0f, 0.0f);
        float4* o4 = reinterpret_cast<float4*>(out + ((size_t)r * C + cbase) * NPIX);
        const int NQ = CG * NPIX / 4;   // 1568
        for (int q = tid; q < NQ; q += 256) o4[q] = z;
    }

    if (tid < 2 * NLEV) (&s_axany[0][0])[tid] = 0;
    if (tid == 0) s_nact = 0;
    __syncthreads();

    // ---- phase 1: coordinate prep (224 work items) ----
    if (tid < 2 * NLEV * GRIDG) {
        int lv   = tid / (2 * GRIDG);
        int rem  = tid - lv * 2 * GRIDG;
        int axis = rem / GRIDG;          // 0 = y, 1 = x
        int g    = rem - axis * GRIDG;

        float x1 = rois[4*r+0], y1 = rois[4*r+1];
        float x2 = rois[4*r+2], y2 = rois[4*r+3];
        for (int j = 3; j >= lv; --j) {   // cumulative scale, reference order
            float f = (float)(28 << j);
            x1 = __fmul_rn(x1, f); y1 = __fmul_rn(y1, f);
            x2 = __fmul_rn(x2, f); y2 = __fmul_rn(y2, f);
        }
        float lo_c = axis ? x1 : y1;
        float hi_c = axis ? x2 : y2;
        int   Li = HS[lv];
        float Lf = (float)Li;

        float span = fmaxf(__fsub_rn(hi_c, lo_c), 1.0f);
        float bin  = __fdiv_rn(span, (float)OUTS);
        float step = ((float)g + 0.5f) * 0.5f;          // (g+0.5)/sr, exact
        float c    = __fadd_rn(lo_c, __fmul_rn(step, bin));

        int valid = (c >= -1.0f) && (c <= Lf);
        float cc  = fminf(fmaxf(c, 0.0f), Lf - 1.0f);
        float fl  = floorf(cc);
        float fr  = __fsub_rn(cc, fl);
        int lo = (int)fl, hi = lo + 1;
        if (lo >= Li - 1) { lo = Li - 1; hi = Li - 1; fr = 0.0f; }

        s_lo[axis][lv][g] = lo;  s_hi[axis][lv][g] = hi;
        s_fr[axis][lv][g] = fr;  s_va[axis][lv][g] = valid;
        if (valid) s_axany[axis][lv] = 1;
    }
    __syncthreads();

    // ---- block-uniform activity mask (per level: both axes have a valid
    //      sample <=> at least pixel (0,0) is active at that level) ----
    int amask = 0;
    #pragma unroll
    for (int lv = 0; lv < NLEV; ++lv)
        amask |= (s_axany[0][lv] & s_axany[1][lv]) << lv;
    if (amask == 0) return;   // ~95% of blocks: zero slab is the final answer

    // ---- phase 2: per-pixel activity + compacted list ----
    if (tid < NPIX) {
        int oy = tid / OUTS, ox = tid - oy * OUTS;
        int gy = 2 * oy, gx = 2 * ox;
        int act = 0;
        #pragma unroll
        for (int lv = 0; lv < NLEV; ++lv) {
            int ay = s_va[0][lv][gy] | s_va[0][lv][gy+1];
            int ax = s_va[1][lv][gx] | s_va[1][lv][gx+1];
            act |= (ay & ax);
        }
        if (act) {
            int pos = atomicAdd(&s_nact, 1);
            s_plist[pos] = tid;
        }
    }
    __syncthreads();   // also orders phase-0 zero stores before the sweep's
                       // value stores (vmcnt(0) drain before s_barrier)

    // ---- phase 3: channel sweep, max across levels in registers, single
    //      store per (channel, active pixel) ----
    const int cl = tid >> 3;          // 0..31 channel within group
    const int k  = tid & 7;
    const int nact = s_nact;
    for (int pi = k; pi < nact; pi += 8) {
        int p  = s_plist[pi];
        int oy = p / OUTS, ox = p - oy * OUTS;
        int gy = 2 * oy, gx = 2 * ox;
        float val = 0.0f;
        #pragma unroll
        for (int lv = 0; lv < NLEV; ++lv) {
            if (!(amask & (1 << lv))) continue;   // block-uniform
            const int W = HS[lv];
            const float* __restrict__ base = fp[lv] + (size_t)(cbase + cl) * W * W;
            float acc = 0.0f;
            #pragma unroll
            for (int sy = 0; sy < 2; ++sy) {
                int   yv  = s_va[0][lv][gy+sy];
                int   ylo = s_lo[0][lv][gy+sy] * W;
                int   yhi = s_hi[0][lv][gy+sy] * W;
                float fy  = s_fr[0][lv][gy+sy];
                #pragma unroll
                for (int sx = 0; sx < 2; ++sx) {
                    int   xv  = s_va[1][lv][gx+sx];
                    int   xlo = s_lo[1][lv][gx+sx];
                    int   xhi = s_hi[1][lv][gx+sx];
                    float fx  = s_fr[1][lv][gx+sx];
                    float m   = (yv & xv) ? 1.0f : 0.0f;
                    // same term order / expression shapes as v2's table path
                    acc += (m * (1.0f-fy) * (1.0f-fx)) * base[ylo + xlo];
                    acc += (m * (1.0f-fy) * fx       ) * base[ylo + xhi];
                    acc += (m * fy        * (1.0f-fx)) * base[yhi + xlo];
                    acc += (m * fy        * fx       ) * base[yhi + xhi];
                }
            }
            val = fmaxf(val, acc * 0.25f);
        }
        out[((size_t)r * C + cbase + cl) * NPIX + p] = val;
    }
}

extern "C" void kernel_launch(void* const* d_in, const int* in_sizes, int n_in,
                              void* d_out, int out_size, void* d_ws, size_t ws_size,
                              hipStream_t stream) {
    const float* f0   = (const float*)d_in[0];
    const float* f1   = (const float*)d_in[1];
    const float* f2   = (const float*)d_in[2];
    const float* f3   = (const float*)d_in[3];
    const float* rois = (const float*)d_in[4];
    float* out = (float*)d_out;

    int R = in_sizes[4] / 4;                 // 512
    int C = in_sizes[3] / (28 * 28);         // 256

    afp_kernel<<<R * NCG, 256, 0, stream>>>(f0, f1, f2, f3, rois, out, R, C);
}

// Round 3
// 149.074 us; speedup vs baseline: 1.0138x; 1.0138x over previous
//
#include <hip/hip_runtime.h>

#define OUTS 14
#define GRIDG 28   // OUTS * sampling_ratio(2)
#define NLEV 4
#define NPIX (OUTS*OUTS)   // 196
#define CG   32            // channels per block
#define NCG  8             // 256 / CG

// v4: v3 + block-uniform EARLY EXIT before any LDS/barrier work.
//
// Evidence (rounds 0-2): our kernel is latency-bound, not BW-bound (v1 moved
// 3x the output bytes of v3 at nearly the same dur). In v3, all 4096 blocks
// ran LDS init + 2 __syncthreads + 224-thread coord prep (with fdiv) after
// their fill; each barrier drains vmcnt(0) mid-block, serializing store-drain
// with coord prep across 16 sequential block generations per CU.
//
// Fix: a conservative-EXACT activity pretest using only the roi's top-left
// corner, computed with the IDENTICAL __fmul_rn cumulative chain phase 1
// uses. For every sample coord c: c = lo_c + (g+0.5)/sr * bin with bin > 0,
// so c > lo_c; validity requires c <= L. Hence lo_c > L (either axis) =>
// that level has zero valid samples — no false negatives, bit-identical
// floats. amask0 == 0 (~95% of blocks, given rois tl in [0,0.6)) => the
// block is a pure streaming fill: 6-7 float4 stores + ~10 VALU + endpgm,
// structurally identical to the rocclr fill kernel that sustains 6.85 TB/s.
// Active blocks (~5%) fall through to the v3 path unchanged (its two
// barriers still order the zero stores before the overwrite stores).
__global__ __launch_bounds__(256) void afp_kernel(
    const float* __restrict__ f0, const float* __restrict__ f1,
    const float* __restrict__ f2, const float* __restrict__ f3,
    const float* __restrict__ rois, float* __restrict__ out,
    int R, int C)
{
    __shared__ int   s_lo[2][NLEV][GRIDG];
    __shared__ int   s_hi[2][NLEV][GRIDG];
    __shared__ float s_fr[2][NLEV][GRIDG];
    __shared__ int   s_va[2][NLEV][GRIDG];
    __shared__ int   s_axany[2][NLEV];
    __shared__ int   s_plist[NPIX];
    __shared__ int   s_nact;

    const int bx  = blockIdx.x;
    const int r   = bx >> 3;
    const int cg  = bx & 7;
    const int tid = threadIdx.x;
    const int HS[NLEV] = {224, 112, 56, 28};
    const float* const fp[NLEV] = {f0, f1, f2, f3};
    const int cbase = cg * CG;

    // ---- phase 0: streaming zero-fill of this block's slab (issued first,
    //      no dependencies) ----
    {
        float4 z = make_float4(0.0f, 0.0f, 0.0f, 0.0f);
        float4* o4 = reinterpret_cast<float4*>(out + ((size_t)r * C + cbase) * NPIX);
        const int NQ = CG * NPIX / 4;   // 1568
        for (int q = tid; q < NQ; q += 256) o4[q] = z;
    }

    // ---- early activity pretest (block-uniform, no LDS, no barrier) ----
    // Same rounding chain as phase 1: running product applies f(3), f(2), ...
    // so after the j-th step the values are exactly phase 1's lv=j coords.
    int amask0;
    {
        float xs = rois[4*r+0], ys = rois[4*r+1];
        amask0 = 0;
        #pragma unroll
        for (int j = 3; j >= 0; --j) {
            float f = (float)(28 << j);
            xs = __fmul_rn(xs, f);
            ys = __fmul_rn(ys, f);
            float Lf = (float)HS[j];
            if (xs <= Lf && ys <= Lf) amask0 |= 1 << j;
        }
    }
    if (amask0 == 0) return;   // ~95% of blocks: pure fill, no barriers hit

    // ================= active path (~5% of blocks) =================
    if (tid < 2 * NLEV) (&s_axany[0][0])[tid] = 0;
    if (tid == 0) s_nact = 0;
    __syncthreads();

    // ---- phase 1: coordinate prep (224 work items) ----
    if (tid < 2 * NLEV * GRIDG) {
        int lv   = tid / (2 * GRIDG);
        int rem  = tid - lv * 2 * GRIDG;
        int axis = rem / GRIDG;          // 0 = y, 1 = x
        int g    = rem - axis * GRIDG;

        float x1 = rois[4*r+0], y1 = rois[4*r+1];
        float x2 = rois[4*r+2], y2 = rois[4*r+3];
        for (int j = 3; j >= lv; --j) {   // cumulative scale, reference order
            float f = (float)(28 << j);
            x1 = __fmul_rn(x1, f); y1 = __fmul_rn(y1, f);
            x2 = __fmul_rn(x2, f); y2 = __fmul_rn(y2, f);
        }
        float lo_c = axis ? x1 : y1;
        float hi_c = axis ? x2 : y2;
        int   Li = HS[lv];
        float Lf = (float)Li;

        float span = fmaxf(__fsub_rn(hi_c, lo_c), 1.0f);
        float bin  = __fdiv_rn(span, (float)OUTS);
        float step = ((float)g + 0.5f) * 0.5f;          // (g+0.5)/sr, exact
        float c    = __fadd_rn(lo_c, __fmul_rn(step, bin));

        int valid = (c >= -1.0f) && (c <= Lf);
        float cc  = fminf(fmaxf(c, 0.0f), Lf - 1.0f);
        float fl  = floorf(cc);
        float fr  = __fsub_rn(cc, fl);
        int lo = (int)fl, hi = lo + 1;
        if (lo >= Li - 1) { lo = Li - 1; hi = Li - 1; fr = 0.0f; }

        s_lo[axis][lv][g] = lo;  s_hi[axis][lv][g] = hi;
        s_fr[axis][lv][g] = fr;  s_va[axis][lv][g] = valid;
        if (valid) s_axany[axis][lv] = 1;
    }
    __syncthreads();

    // ---- block-uniform exact activity mask ----
    int amask = 0;
    #pragma unroll
    for (int lv = 0; lv < NLEV; ++lv)
        amask |= (s_axany[0][lv] & s_axany[1][lv]) << lv;
    if (amask == 0) return;   // pretest false-positive: zero slab is final

    // ---- phase 2: per-pixel activity + compacted list ----
    if (tid < NPIX) {
        int oy = tid / OUTS, ox = tid - oy * OUTS;
        int gy = 2 * oy, gx = 2 * ox;
        int act = 0;
        #pragma unroll
        for (int lv = 0; lv < NLEV; ++lv) {
            int ay = s_va[0][lv][gy] | s_va[0][lv][gy+1];
            int ax = s_va[1][lv][gx] | s_va[1][lv][gx+1];
            act |= (ay & ax);
        }
        if (act) {
            int pos = atomicAdd(&s_nact, 1);
            s_plist[pos] = tid;
        }
    }
    __syncthreads();   // also orders phase-0 zero stores before the sweep's
                       // value stores (vmcnt(0) drain before s_barrier)

    // ---- phase 3: channel sweep, max across levels in registers, single
    //      store per (channel, active pixel) ----
    const int cl = tid >> 3;          // 0..31 channel within group
    const int k  = tid & 7;
    const int nact = s_nact;
    for (int pi = k; pi < nact; pi += 8) {
        int p  = s_plist[pi];
        int oy = p / OUTS, ox = p - oy * OUTS;
        int gy = 2 * oy, gx = 2 * ox;
        float val = 0.0f;
        #pragma unroll
        for (int lv = 0; lv < NLEV; ++lv) {
            if (!(amask & (1 << lv))) continue;   // block-uniform
            const int W = HS[lv];
            const float* __restrict__ base = fp[lv] + (size_t)(cbase + cl) * W * W;
            float acc = 0.0f;
            #pragma unroll
            for (int sy = 0; sy < 2; ++sy) {
                int   yv  = s_va[0][lv][gy+sy];
                int   ylo = s_lo[0][lv][gy+sy] * W;
                int   yhi = s_hi[0][lv][gy+sy] * W;
                float fy  = s_fr[0][lv][gy+sy];
                #pragma unroll
                for (int sx = 0; sx < 2; ++sx) {
                    int   xv  = s_va[1][lv][gx+sx];
                    int   xlo = s_lo[1][lv][gx+sx];
                    int   xhi = s_hi[1][lv][gx+sx];
                    float fx  = s_fr[1][lv][gx+sx];
                    float m   = (yv & xv) ? 1.0f : 0.0f;
                    acc += (m * (1.0f-fy) * (1.0f-fx)) * base[ylo + xlo];
                    acc += (m * (1.0f-fy) * fx       ) * base[ylo + xhi];
                    acc += (m * fy        * (1.0f-fx)) * base[yhi + xlo];
                    acc += (m * fy        * fx       ) * base[yhi + xhi];
                }
            }
            val = fmaxf(val, acc * 0.25f);
        }
        out[((size_t)r * C + cbase + cl) * NPIX + p] = val;
    }
}

extern "C" void kernel_launch(void* const* d_in, const int* in_sizes, int n_in,
                              void* d_out, int out_size, void* d_ws, size_t ws_size,
                              hipStream_t stream) {
    const float* f0   = (const float*)d_in[0];
    const float* f1   = (const float*)d_in[1];
    const float* f2   = (const float*)d_in[2];
    const float* f3   = (const float*)d_in[3];
    const float* rois = (const float*)d_in[4];
    float* out = (float*)d_out;

    int R = in_sizes[4] / 4;                 // 512
    int C = in_sizes[3] / (28 * 28);         // 256

    afp_kernel<<<R * NCG, 256, 0, stream>>>(f0, f1, f2, f3, rois, out, R, C);
}